// Round 1
// baseline (133.378 us; speedup 1.0000x reference)
//
#include <hip/hip_runtime.h>
#include <hip/hip_bf16.h>
#include <cfloat>

// B=32, N=2048 -> BN=65536 rows, D=128, K=1024 codes
#define DIM 128
#define NCODES 1024
#define MTILE 128            // rows per block = 4 waves x 32 rows
#define ROWS_PER_WAVE 32
#define NSUB 2               // 16-row M-subtiles per wave
#define KSTEPS 4             // K=128 / 32
#define CODES_PER_STEP 32    // codes staged to LDS per step
#define NSTEPS (NCODES / CODES_PER_STEP)  // 32
#define STEP_F16 8192        // f16 elems per packed step tile (16 KB = hi plane + lo plane)
#define PLANE_F16 4096
#define STEP_BYTES 16384
#define LOSS_SCALE (12.5f / 8388608.0f)

typedef _Float16 f16x8 __attribute__((ext_vector_type(8)));
typedef float f32x4 __attribute__((ext_vector_type(4)));

// Direct global->LDS DMA, 16 B per lane. LDS dest is wave-uniform base +
// lane*16 (HW rule); global src is per-lane.
__device__ __forceinline__ void gld16(const void* g, void* l) {
    __builtin_amdgcn_global_load_lds((const __attribute__((address_space(1))) void*)g,
                                     (__attribute__((address_space(3))) void*)l, 16, 0, 0);
}

// prep: E (fp32) -> Epk: packed, staging-ready f16 hi/lo image + enorm = ||E_k||^2.
// Epk layout (f16 units), designed so vq's ds_reads are lane-linear:
//   P(code,k,plane) = st*8192 + plane*4096 + (ks*2+u)*512 + (quad*16+m16)*8 + j
// where st=code>>5, u=(code>>4)&1, m16=code&15, ks=k>>5, quad=(k>>3)&3, j=k&7.
// Each (u,ks,plane) fragment-group is a contiguous 1 KB segment where lane
// l=(quad*16+m16) owns bytes [l*16, l*16+16) -> conflict-free ds_read_b128
// from one address register + immediate offsets. Block 0 zeroes loss.
__global__ __launch_bounds__(128) void prep_kernel(const float* __restrict__ E,
                                                   _Float16* __restrict__ Epk,
                                                   float* __restrict__ enorm,
                                                   float* __restrict__ loss) {
    const int k = blockIdx.x;   // code
    const int d = threadIdx.x;  // dim
    if (k == 0 && d == 0) *loss = 0.f;
    float e = E[k * DIM + d];
    _Float16 h = (_Float16)e;
    _Float16 l = (_Float16)(e - (float)h);
    const int st = k >> 5, u = (k >> 4) & 1, m16 = k & 15;
    const int ks = d >> 5, quad = (d >> 3) & 3, j = d & 7;
    const int addr = st * STEP_F16 + (ks * 2 + u) * 512 + ((quad << 4) + m16) * 8 + j;
    Epk[addr] = h;
    Epk[addr + PLANE_F16] = l;
    float sq = e * e;
#pragma unroll
    for (int off = 32; off > 0; off >>= 1) sq += __shfl_down(sq, off, 64);
    __shared__ float s2[2];
    if ((d & 63) == 0) s2[d >> 6] = sq;
    __syncthreads();
    if (d == 0) enorm[k] = s2[0] + s2[1];
}

// Fused MFMA dist + argmin + gather + loss.
// r7 (this round): replace reg-staged LDS staging with global_load_lds from a
// pre-permuted codebook image. Old path exposed ~250-900 cyc of L2 latency per
// step (global_load -> vmcnt(0) -> ds_write serial chain, compiler can't sink
// the writes past the MFMA loop) and BPITCH=136 reads cost 4.19M bank-conflict
// cycles (68-dword stride == 4 mod 32). New path: zero ds_writes, loads drain
// only at the end-of-step barrier (whole compute phase to land), and every
// ds_read_b128 is uniform-base + lane*16 (m134 conflict-free pattern).
// Numerics bit-identical to r6 (same hi/lo split, same MFMA order).
// r3 lesson: no runtime-indexed register arrays. r5 lesson: stay on (256,2).
__global__ __launch_bounds__(256, 2) void vq_kernel(const float* __restrict__ z,
                                                    const _Float16* __restrict__ Epk,
                                                    const float* __restrict__ enorm,
                                                    const float* __restrict__ E,
                                                    float* __restrict__ out,
                                                    float* __restrict__ loss) {
    const int t = threadIdx.x;
    const int lane = t & 63;
    const int wave = t >> 6;     // row-wave: rows [wave*32, wave*32+32)
    const int m16 = lane & 15;   // A row within subtile / B,C code col
    const int quad = lane >> 4;  // k-group for A/B; row-group for C

    __shared__ __attribute__((aligned(16))) _Float16 s_b[2][STEP_F16];  // 2 x 16 KB
    __shared__ __attribute__((aligned(16))) float s_enorm[NCODES];      // 4096 B
    __shared__ float s_znorm[MTILE];
    __shared__ int s_ind[MTILE];
    __shared__ float s_wsum[4];

    // enorm -> LDS via DMA (4 waves x 1024 B); drained by the first barrier.
    gld16((const char*)enorm + wave * 1024 + lane * 16, (char*)s_enorm + wave * 1024);

    // ---- A fragments: wave's 32 rows, K=128, scaled by -2, f16 hi/lo split.
    // A layout (16x16x32): lane holds A[m=lane&15][k=quad*8+j], j=0..7.
    f16x8 Ahi[NSUB][KSTEPS], Alo[NSUB][KSTEPS];
    float znp[NSUB] = {0.f, 0.f};
    const int rowbase = blockIdx.x * MTILE + wave * ROWS_PER_WAVE;
#pragma unroll
    for (int s = 0; s < NSUB; ++s) {
        const int row = rowbase + s * 16 + m16;
        const float* zp = z + (size_t)row * DIM + quad * 8;
#pragma unroll
        for (int ks = 0; ks < KSTEPS; ++ks) {
            float4 v0 = *(const float4*)(zp + ks * 32);
            float4 v1 = *(const float4*)(zp + ks * 32 + 4);
            float zv[8] = {v0.x, v0.y, v0.z, v0.w, v1.x, v1.y, v1.z, v1.w};
#pragma unroll
            for (int j = 0; j < 8; ++j) {
                znp[s] = fmaf(zv[j], zv[j], znp[s]);
                float tt = -2.f * zv[j];
                _Float16 h = (_Float16)tt;
                Ahi[s][ks][j] = h;
                Alo[s][ks][j] = (_Float16)(tt - (float)h);
            }
        }
    }
    // znorm per row -> LDS (consumed after loop; loop barriers order it)
#pragma unroll
    for (int s = 0; s < NSUB; ++s) {
        float v = znp[s];
        v += __shfl_xor(v, 16, 64);
        v += __shfl_xor(v, 32, 64);
        if (quad == 0) s_znorm[wave * ROWS_PER_WAVE + s * 16 + m16] = v;
    }

    float bestv[NSUB][4];
    int besti[NSUB][4];
#pragma unroll
    for (int s = 0; s < NSUB; ++s)
#pragma unroll
        for (int r = 0; r < 4; ++r) {
            bestv[s][r] = FLT_MAX;
            besti[s][r] = 0;
        }

    // Stage step ST's packed 16 KB tile into LDS buffer B via global_load_lds.
    // 16 chunks of 1 KB; wave w DMAs chunks {w, w+4, w+8, w+12}. Source address
    // carries lane*16; LDS dest is the wave-uniform chunk base (HW adds lane*16).
#define STAGE(ST, B)                                                              \
    {                                                                             \
        const char* gsb = (const char*)Epk + (size_t)(ST)*STEP_BYTES + lane * 16; \
        char* lsb = (char*)s_b[B];                                                \
        gld16(gsb + (wave + 0) * 1024, lsb + (wave + 0) * 1024);                  \
        gld16(gsb + (wave + 4) * 1024, lsb + (wave + 4) * 1024);                  \
        gld16(gsb + (wave + 8) * 1024, lsb + (wave + 8) * 1024);                  \
        gld16(gsb + (wave + 12) * 1024, lsb + (wave + 12) * 1024);                \
    }

    STAGE(0, 0)
    __syncthreads();

    int buf = 0;
    for (int st = 0; st < NSTEPS; ++st) {
        if (st + 1 < NSTEPS) STAGE(st + 1, buf ^ 1)  // lands during compute below
        const _Float16* bb = s_b[buf];
#pragma unroll
        for (int u = 0; u < 2; ++u) {  // two 16-code subgroups
            f16x8 Bh[KSTEPS], Bl[KSTEPS];
#pragma unroll
            for (int ks = 0; ks < KSTEPS; ++ks) {
                const int o = (ks * 2 + u) * 512 + lane * 8;  // f16 units
                Bh[ks] = *(const f16x8*)(bb + o);
                Bl[ks] = *(const f16x8*)(bb + PLANE_F16 + o);
            }
            f32x4 acc_hh[NSUB], acc_c[NSUB];
#pragma unroll
            for (int s = 0; s < NSUB; ++s) {
                acc_hh[s] = (f32x4){0.f, 0.f, 0.f, 0.f};
                acc_c[s] = (f32x4){0.f, 0.f, 0.f, 0.f};
            }
#pragma unroll
            for (int ks = 0; ks < KSTEPS; ++ks)
#pragma unroll
                for (int s = 0; s < NSUB; ++s) {
                    acc_c[s] = __builtin_amdgcn_mfma_f32_16x16x32_f16(Ahi[s][ks], Bl[ks], acc_c[s], 0, 0, 0);
                    acc_c[s] = __builtin_amdgcn_mfma_f32_16x16x32_f16(Alo[s][ks], Bh[ks], acc_c[s], 0, 0, 0);
                    acc_hh[s] = __builtin_amdgcn_mfma_f32_16x16x32_f16(Ahi[s][ks], Bh[ks], acc_hh[s], 0, 0, 0);
                }
            const int n = st * CODES_PER_STEP + u * 16 + m16;
            const float e = s_enorm[n];
            // C layout: col = lane&15 (code), row = quad*4 + r
#pragma unroll
            for (int s = 0; s < NSUB; ++s)
#pragma unroll
                for (int r = 0; r < 4; ++r) {
                    float d = (acc_hh[s][r] + acc_c[s][r]) + e;
                    if (d < bestv[s][r]) {  // strict <, ascending n per lane => first-index
                        bestv[s][r] = d;
                        besti[s][r] = n;
                    }
                }
        }
        __syncthreads();  // drains st+1 DMA; buf safe to overwrite at st+2
        buf ^= 1;
    }
#undef STAGE

    // ---- in-wave argmin across the 16 m16-lanes (xor butterflies stay in-quad;
    // lexicographic (v,i) merge == global first-index rule)
#pragma unroll
    for (int s = 0; s < NSUB; ++s)
#pragma unroll
        for (int r = 0; r < 4; ++r) {
            float v = bestv[s][r];
            int i = besti[s][r];
#pragma unroll
            for (int m = 1; m <= 8; m <<= 1) {
                float ov = __shfl_xor(v, m, 64);
                int oi = __shfl_xor(i, m, 64);
                if (ov < v || (ov == v && oi < i)) {
                    v = ov;
                    i = oi;
                }
            }
            bestv[s][r] = v;
            besti[s][r] = i;
        }

    float lp = 0.f;
    if (m16 == 0) {  // one winner lane per quad; owns rows quad*4+r (+s*16)
#pragma unroll
        for (int s = 0; s < NSUB; ++s)
#pragma unroll
            for (int r = 0; r < 4; ++r) {
                const int row = wave * ROWS_PER_WAVE + s * 16 + quad * 4 + r;
                s_ind[row] = besti[s][r];
                lp += s_znorm[row] + bestv[s][r];  // ||z-E||^2 = ||z||^2 + dist'
            }
    }
    lp += __shfl_xor(lp, 16, 64);  // lanes {0,16,32,48} hold partials
    lp += __shfl_xor(lp, 32, 64);
    if (lane == 0) s_wsum[wave] = lp;
    __syncthreads();
    if (t == 0)
        atomicAdd(loss, (s_wsum[0] + s_wsum[1] + s_wsum[2] + s_wsum[3]) * LOSS_SCALE);

    // ---- gather-write z_q (STE forward == z_q), float4 coalesced, E is L2-hot
    const float4* E4 = (const float4*)E;
    float4* out4 = (float4*)(out + (size_t)blockIdx.x * (MTILE * DIM));
#pragma unroll
    for (int i = 0; i < (MTILE * DIM) / (256 * 4); ++i) {
        const int f = t + i * 256;  // float4 index within tile
        const int r = f >> 5;       // 32 float4 per row
        const int d = f & 31;
        out4[f] = E4[(size_t)s_ind[r] * 32 + d];
    }
}

extern "C" void kernel_launch(void* const* d_in, const int* in_sizes, int n_in,
                              void* d_out, int out_size, void* d_ws, size_t ws_size,
                              hipStream_t stream) {
    const float* z = (const float*)d_in[0];  // [BN,128] fp32
    const float* E = (const float*)d_in[1];  // [1024,128] fp32
    float* out = (float*)d_out;              // [BN*128] z_q + [1] loss
    float* loss = out + (size_t)(out_size - 1);
    _Float16* Epk = (_Float16*)d_ws;                          // 512 KB packed image
    float* enorm = (float*)((char*)d_ws + (size_t)NCODES * DIM * 2 * sizeof(_Float16));  // 4 KB
    const int BN = in_sizes[0] / DIM;

    prep_kernel<<<NCODES, 128, 0, stream>>>(E, Epk, enorm, loss);
    vq_kernel<<<BN / MTILE, 256, 0, stream>>>(z, Epk, enorm, E, out, loss);
}